// Round 4
// baseline (861.863 us; speedup 1.0000x reference)
//
#include <hip/hip_runtime.h>
#include <hip/hip_bf16.h>
#include <math.h>

// Problem constants
#define NB   1024   // batch
#define NT   60     // time steps
#define NC   10     // in channels
#define NDM  256    // d_model
#define NH   16     // heads
#define NDH  16     // per-head value dim
#define NA   13     // num attention queries
#define NM   208    // NA*NH
#define NMO  128    // MLP out

// Workspace layout (floats)
#define OFF_WEFF  0
#define N_WEFF    (NM*NH*NDM*NA)               // 11,075,584
#define OFF_BEFF  (OFF_WEFF + N_WEFF)
#define N_BEFF    (NM*NH*NA)                   // 43,264
#define OFF_ATT   (OFF_BEFF + N_BEFF)
#define N_ATT     (NM*NB*NDH)                  // 3,407,872

// ---------------- K0: weff[m][hk][d][ak] = sum_dk Q[m,dk]*Wk[(ak*16+hk)*4+dk, d]
__global__ void ltae_weff(const float* __restrict__ Q, const float* __restrict__ Wk,
                          const float* __restrict__ bk, float* __restrict__ weff2,
                          float* __restrict__ beff2) {
    int blk = blockIdx.x;            // m*16 + hk
    int m = blk >> 4, hk = blk & 15;
    int d = threadIdx.x;
    float q0 = Q[m*4+0], q1 = Q[m*4+1], q2 = Q[m*4+2], q3 = Q[m*4+3];
    float outv[NA];
#pragma unroll
    for (int ak = 0; ak < NA; ++ak) {
        int e = (ak*16 + hk)*4;
        outv[ak] = q0*Wk[(size_t)(e+0)*NDM + d] + q1*Wk[(size_t)(e+1)*NDM + d]
                 + q2*Wk[(size_t)(e+2)*NDM + d] + q3*Wk[(size_t)(e+3)*NDM + d];
    }
    size_t base = ((size_t)blk*NDM + d)*NA;
#pragma unroll
    for (int ak = 0; ak < NA; ++ak) weff2[base + ak] = outv[ak];
    if (d < NA) {
        int e = (d*16 + hk)*4;
        beff2[blk*NA + d] = q0*bk[e] + q1*bk[e+1] + q2*bk[e+2] + q3*bk[e+3];
    }
}

// ---------------- K2: fused conv+GN + scrambled attention; block = b, wave = hk
// LDS: Vt fp32 [256][68] + C fp32 [16 waves][784]
#define VT_S   68
#define VT_F   (NDM*VT_S)            // 17,408 floats
#define C_F    (NH*784)              // 12,544 floats
#define K2_LDS_BYTES ((VT_F + C_F)*4)  // 119,808 B -> 1 block/CU, 16 waves

__launch_bounds__(1024, 4)
__global__ void ltae_fused(const float* __restrict__ x, const float* __restrict__ Wc,
                           const float* __restrict__ bc, const float* __restrict__ gnw,
                           const float* __restrict__ gnb, const float* __restrict__ weff2,
                           const float* __restrict__ beff2, float* __restrict__ attout) {
    extern __shared__ float smem[];
    float* Vt = smem;
    float* Cb = smem + VT_F;

    int b = blockIdx.x, tid = threadIdx.x;

    // ---- stage x[b] (600 floats) into C region (dead until GEMM dump)
    float* xs = Cb;
    if (tid < NT*NC) xs[tid] = x[(size_t)b*NT*NC + tid];
    __syncthreads();

    // ---- conv 1x1 + GroupNorm(16 groups over 16ch x 60t), write Vt fp32 [d][t]
    {
        int d = tid >> 2, q = tid & 3;   // wave w covers d in [16w,16w+16) = GN group w
        float wc[NC];
#pragma unroll
        for (int c = 0; c < NC; ++c) wc[c] = Wc[d*NC + c];
        float bcv = bc[d];
        float h[15];
        float s1 = 0.f, s2 = 0.f;
#pragma unroll
        for (int k = 0; k < 15; ++k) {
            int t = 15*q + k;
            float a = bcv;
#pragma unroll
            for (int c = 0; c < NC; ++c) a = fmaf(xs[t*NC + c], wc[c], a);
            h[k] = a; s1 += a; s2 += a*a;
        }
#pragma unroll
        for (int off = 1; off < 64; off <<= 1) {
            s1 += __shfl_xor(s1, off);
            s2 += __shfl_xor(s2, off);
        }
        float mean = s1 * (1.f/960.f);
        float var  = s2 * (1.f/960.f) - mean*mean;
        float rstd = rsqrtf(var + 1e-5f);
        float g = gnw[d], bb = gnb[d];
#pragma unroll
        for (int k = 0; k < 15; ++k) {
            int t = 15*q + k;
            Vt[d*VT_S + t] = (h[k]-mean)*rstd*g + bb;
        }
        if (q == 0) {
#pragma unroll
            for (int t = NT; t < VT_S; ++t) Vt[d*VT_S + t] = 0.f;
        }
    }
    __syncthreads();

    // ---- per-wave attention: wave = hk (kept DIVERGENT in compiler's view so
    // weight loads stay VMEM/vmcnt, not SMEM/lgkmcnt — SMEM returns are
    // out-of-order and share lgkmcnt with ds_read, forcing full drains)
    int wid = tid >> 6, lane = tid & 63;
    int hk = wid;
    int tk = lane;
    int hb13  = (hk*1024 + b)*13;
    int m0    = hb13 >> 10;
    int rstar = ((m0+1) << 10) - hb13;              // 1..1024; variant switch if <13

    float acc[13];
#pragma unroll
    for (int j = 0; j < 13; ++j) acc[j] = 0.f;

    // pass A: weight row m0 via vector loads (vmcnt domain, in-order, pipelineable)
    {
        const float4* __restrict__ wr = (const float4*)(weff2 + ((size_t)(m0*16 + hk))*NDM*NA);
        for (int d4 = 0; d4 < 64; ++d4) {
            float4 w[13];
#pragma unroll
            for (int i = 0; i < 13; ++i) w[i] = wr[d4*13 + i];
            float v[4];
#pragma unroll
            for (int dd = 0; dd < 4; ++dd) v[dd] = Vt[(4*d4+dd)*VT_S + tk];
#pragma unroll
            for (int dd = 0; dd < 4; ++dd)
#pragma unroll
                for (int ak = 0; ak < 13; ++ak) {
                    int e = dd*13 + ak;
                    float we = ((const float*)w)[e];
                    acc[ak] = fmaf(v[dd], we, acc[ak]);
                }
        }
    }
    // pass B (rare boundary waves): weight row m0+1, exact per-(tk,ak) select
    if (rstar < 13) {
        float accB[13];
#pragma unroll
        for (int j = 0; j < 13; ++j) accB[j] = 0.f;
        const float4* __restrict__ wr = (const float4*)(weff2 + ((size_t)((m0+1)*16 + hk))*NDM*NA);
        for (int d4 = 0; d4 < 64; ++d4) {
            float4 w[13];
#pragma unroll
            for (int i = 0; i < 13; ++i) w[i] = wr[d4*13 + i];
            float v[4];
#pragma unroll
            for (int dd = 0; dd < 4; ++dd) v[dd] = Vt[(4*d4+dd)*VT_S + tk];
#pragma unroll
            for (int dd = 0; dd < 4; ++dd)
#pragma unroll
                for (int ak = 0; ak < 13; ++ak) {
                    int e = dd*13 + ak;
                    float we = ((const float*)w)[e];
                    accB[ak] = fmaf(v[dd], we, accB[ak]);
                }
        }
#pragma unroll
        for (int j = 0; j < 13; ++j)
            if (13*tk + j >= 60*rstar) acc[j] = accB[j];
    }

    // ---- dump C in u-layout (u = 13*tk + ak); wave-private row, no block barrier
    float* Crow = Cb + hk*784;
    if (tk < NT) {
#pragma unroll
        for (int j = 0; j < 13; ++j) Crow[13*tk + j] = acc[j];
    }
    __asm__ __volatile__("s_waitcnt lgkmcnt(0)" ::: "memory");

    // ---- softmax + AV per r (13 rows), all within this wave, fp32 throughout
    int dh = lane >> 2, cc = lane & 3;
    const float* vrow = Vt + (hk*16 + dh)*VT_S;
    for (int r = 0; r < 13; ++r) {
        int n = hb13 + r;
        int m = n >> 10;                             // exact weight/bias variant for this row
        int brow = (m*16 + hk)*13;
        float logit = -1e30f;
        if (lane < NT) {
            int u  = r*60 + lane;
            int ak = u % 13;
            logit = (Crow[u] + beff2[brow + ak]) * 0.5f;
        }
        float mx = logit;
#pragma unroll
        for (int off = 32; off; off >>= 1) mx = fmaxf(mx, __shfl_xor(mx, off));
        float e = (lane < NT) ? __expf(logit - mx) : 0.f;
        float s = e;
#pragma unroll
        for (int off = 32; off; off >>= 1) s += __shfl_xor(s, off);
        float attn = e / s;
        // store attn in-place over the already-consumed C row (same-wave, in-order LDS)
        if (lane < NT) Crow[r*60 + lane] = attn;
        __asm__ __volatile__("s_waitcnt lgkmcnt(0)" ::: "memory");
        // AV: lane = dh*4+cc; t = cc+4j covers 0..59 exactly
        float a = 0.f;
#pragma unroll
        for (int j = 0; j < 15; ++j) {
            int t = cc + 4*j;
            a = fmaf(Crow[r*60 + t], vrow[t], a);
        }
        a += __shfl_xor(a, 1);
        a += __shfl_xor(a, 2);
        if (cc == 0) attout[(size_t)n*NDH + dh] = a;
    }
}

// ---------------- K3: MLP + BN(eval) + ReLU + GroupNorm(16,128); 8 rows/block
__launch_bounds__(1024)
__global__ void ltae_mlp(const float* __restrict__ attout, const float* __restrict__ W1,
                         const float* __restrict__ b1, const float* __restrict__ bnw,
                         const float* __restrict__ bnb, const float* __restrict__ bnrm,
                         const float* __restrict__ bnrv, const float* __restrict__ gow,
                         const float* __restrict__ gob, float* __restrict__ out) {
    __shared__ float f[8][NDM];
    int tid = threadIdx.x;
    int sl  = tid >> 7;          // 0..7 row slot
    int j   = tid & 127;
    int sid = (blockIdx.x << 3) + sl;   // sid = a2*1024 + b2
    int a2  = sid >> 10, b2 = sid & 1023;
    // stage 8 rows of gathered features
    for (int k = tid; k < 8*NDM; k += 1024) {
        int s = k >> 8, c = k & 255;
        int sid2 = (blockIdx.x << 3) + s;
        int aa = sid2 >> 10, bb = sid2 & 1023;
        int h2 = c >> 4, dhh = c & 15;
        f[s][c] = attout[((size_t)((aa*16 + h2)*1024 + bb))*NDH + dhh];
    }
    __syncthreads();
    const float* fr = f[sl];
    const float* w  = &W1[(size_t)j*NDM];
    float acc = b1[j];
    for (int c = 0; c < NDM; c += 4) {
        float4 wv = *(const float4*)&w[c];
        acc += wv.x*fr[c] + wv.y*fr[c+1] + wv.z*fr[c+2] + wv.w*fr[c+3];
    }
    float y = (acc - bnrm[j]) * rsqrtf(bnrv[j] + 1e-5f) * bnw[j] + bnb[j];
    y = fmaxf(y, 0.f);
    float s1 = y, s2 = y*y;
#pragma unroll
    for (int off = 1; off < 8; off <<= 1) {
        s1 += __shfl_xor(s1, off);
        s2 += __shfl_xor(s2, off);
    }
    float mean = s1 * 0.125f;
    float var  = s2 * 0.125f - mean*mean;
    float o = (y - mean) * rsqrtf(var + 1e-5f) * gow[j] + gob[j];
    out[((size_t)b2*NA + a2)*NMO + j] = o;
}

extern "C" void kernel_launch(void* const* d_in, const int* in_sizes, int n_in,
                              void* d_out, int out_size, void* d_ws, size_t ws_size,
                              hipStream_t stream) {
    const float* x    = (const float*)d_in[0];
    const float* Wc   = (const float*)d_in[1];
    const float* bc   = (const float*)d_in[2];
    const float* gnw  = (const float*)d_in[3];
    const float* gnb  = (const float*)d_in[4];
    const float* Q    = (const float*)d_in[5];
    const float* Wk   = (const float*)d_in[6];
    const float* bk   = (const float*)d_in[7];
    const float* W1   = (const float*)d_in[8];
    const float* b1   = (const float*)d_in[9];
    const float* bnw  = (const float*)d_in[10];
    const float* bnb  = (const float*)d_in[11];
    const float* bnrm = (const float*)d_in[12];
    const float* bnrv = (const float*)d_in[13];
    const float* gow  = (const float*)d_in[14];
    const float* gob  = (const float*)d_in[15];

    float* ws     = (float*)d_ws;
    float* weff2  = ws + OFF_WEFF;
    float* beff2  = ws + OFF_BEFF;
    float* attout = ws + OFF_ATT;
    float* outp   = (float*)d_out;

    hipLaunchKernelGGL(ltae_weff, dim3(NM*NH), dim3(256), 0, stream, Q, Wk, bk, weff2, beff2);
    hipFuncSetAttribute((const void*)ltae_fused,
                        hipFuncAttributeMaxDynamicSharedMemorySize, K2_LDS_BYTES);
    hipLaunchKernelGGL(ltae_fused, dim3(NB), dim3(1024), K2_LDS_BYTES, stream,
                       x, Wc, bc, gnw, gnb, weff2, beff2, attout);
    hipLaunchKernelGGL(ltae_mlp, dim3(NA*NB/8), dim3(1024), 0, stream,
                       attout, W1, b1, bnw, bnb, bnrm, bnrv, gow, gob, outp);
}

// Round 5
// 499.202 us; speedup vs baseline: 1.7265x; 1.7265x over previous
//
#include <hip/hip_runtime.h>
#include <hip/hip_bf16.h>
#include <math.h>

// Problem constants
#define NB   1024   // batch
#define NT   60     // time steps
#define NC   10     // in channels
#define NDM  256    // d_model
#define NH   16     // heads
#define NDH  16     // per-head value dim
#define NA   13     // num attention queries
#define NM   208    // NA*NH
#define NMO  128    // MLP out
#define WROW (NDM*NA)   // 3328 floats per weight row

// Workspace layout (floats)
#define OFF_WEFF  0
#define N_WEFF    (NH*14*WROW)                 // 745,472 (compact: only used (hk,mi))
#define OFF_BEFF  (OFF_WEFF + N_WEFF)
#define N_BEFF    (NM*NH*NA)                   // 43,264 (full-size, sparse-filled)
#define OFF_ATT   (OFF_BEFF + N_BEFF)
#define N_ATT     (NM*NB*NDH)                  // 3,407,872

// ---------------- K0: compact weff3[hk][mi][d*13+ak], m = 13*hk+mi
__global__ void ltae_weff(const float* __restrict__ Q, const float* __restrict__ Wk,
                          const float* __restrict__ bk, float* __restrict__ weff3,
                          float* __restrict__ beff2) {
    int blk = blockIdx.x;            // hk*14 + mi
    int hk = blk / 14, mi = blk - hk*14;
    int m  = hk*13 + mi;
    int mc = m > 207 ? 207 : m;      // slot (15,13) is provably never read
    int d = threadIdx.x;
    float q0 = Q[mc*4+0], q1 = Q[mc*4+1], q2 = Q[mc*4+2], q3 = Q[mc*4+3];
    float outv[NA];
#pragma unroll
    for (int ak = 0; ak < NA; ++ak) {
        int e = (ak*16 + hk)*4;
        outv[ak] = q0*Wk[(size_t)(e+0)*NDM + d] + q1*Wk[(size_t)(e+1)*NDM + d]
                 + q2*Wk[(size_t)(e+2)*NDM + d] + q3*Wk[(size_t)(e+3)*NDM + d];
    }
    size_t base = ((size_t)blk*NDM + d)*NA;
#pragma unroll
    for (int ak = 0; ak < NA; ++ak) weff3[base + ak] = outv[ak];
    if (d < NA && m <= 207) {
        int e = (d*16 + hk)*4;
        beff2[(m*16 + hk)*NA + d] = q0*bk[e] + q1*bk[e+1] + q2*bk[e+2] + q3*bk[e+3];
    }
}

// ---------------- K2: fused conv+GN + scrambled attention; block = b, wave = hk
// LDS: Vt fp32 [256][65] + per-wave phased C [16][180]  => 78,080 B => 2 blocks/CU
#define VT_S   65
#define VT_F   (NDM*VT_S)            // 16,640 floats
#define C_S    180
#define C_F    (NH*C_S)              // 2,880 floats
#define K2_LDS_BYTES ((VT_F + C_F)*4)  // 78,080 B

__launch_bounds__(1024, 8)
__global__ void ltae_fused(const float* __restrict__ x, const float* __restrict__ Wc,
                           const float* __restrict__ bc, const float* __restrict__ gnw,
                           const float* __restrict__ gnb, const float* __restrict__ weff3,
                           const float* __restrict__ beff2, float* __restrict__ attout) {
    extern __shared__ float smem[];
    float* Vt = smem;
    float* Cb = smem + VT_F;

    int b = blockIdx.x, tid = threadIdx.x;

    // ---- stage x[b] (600 floats) into C region (dead until GEMM dump)
    float* xs = Cb;
    if (tid < NT*NC) xs[tid] = x[(size_t)b*NT*NC + tid];
    __syncthreads();

    // ---- conv 1x1 + GroupNorm(16 groups over 16ch x 60t), write Vt fp32 [d][t]
    {
        int d = tid >> 2, q = tid & 3;   // wave w covers d in [16w,16w+16) = GN group w
        float wc[NC];
#pragma unroll
        for (int c = 0; c < NC; ++c) wc[c] = Wc[d*NC + c];
        float bcv = bc[d];
        float h[15];
        float s1 = 0.f, s2 = 0.f;
#pragma unroll
        for (int k = 0; k < 15; ++k) {
            int t = 15*q + k;
            float a = bcv;
#pragma unroll
            for (int c = 0; c < NC; ++c) a = fmaf(xs[t*NC + c], wc[c], a);
            h[k] = a; s1 += a; s2 += a*a;
        }
#pragma unroll
        for (int off = 1; off < 64; off <<= 1) {
            s1 += __shfl_xor(s1, off);
            s2 += __shfl_xor(s2, off);
        }
        float mean = s1 * (1.f/960.f);
        float var  = s2 * (1.f/960.f) - mean*mean;
        float rstd = rsqrtf(var + 1e-5f);
        float g = gnw[d], bb = gnb[d];
#pragma unroll
        for (int k = 0; k < 15; ++k) {
            int t = 15*q + k;
            Vt[d*VT_S + t] = (h[k]-mean)*rstd*g + bb;
        }
        if (q == 0) {
#pragma unroll
            for (int t = NT; t < VT_S; ++t) Vt[d*VT_S + t] = 0.f;
        }
    }
    __syncthreads();

    // ---- per-wave attention: wave = hk, lane = tk (SMEM weight path)
    int wid = tid >> 6, lane = tid & 63;
    int hk = __builtin_amdgcn_readfirstlane(wid);   // force SGPR -> uniform weight ptr
    int tk = lane;
    int hb13  = (hk*1024 + b)*13;
    int m0    = hb13 >> 10;
    int mi    = m0 - hk*13;                          // 0..12
    int rstar = ((m0+1) << 10) - hb13;               // 1..1024; variant switch if <13

    float acc[13];
#pragma unroll
    for (int j = 0; j < 13; ++j) acc[j] = 0.f;

    // pass A: weight row mi (wave-uniform -> scalar-load path, weights L2-resident)
    {
        const float4* __restrict__ wr = (const float4*)(weff3 + (size_t)(hk*14 + mi)*WROW);
        for (int d4 = 0; d4 < 64; ++d4) {
            float4 w[13];
#pragma unroll
            for (int i = 0; i < 13; ++i) w[i] = wr[d4*13 + i];
            float v[4];
#pragma unroll
            for (int dd = 0; dd < 4; ++dd) v[dd] = Vt[(4*d4+dd)*VT_S + tk];
#pragma unroll
            for (int dd = 0; dd < 4; ++dd)
#pragma unroll
                for (int ak = 0; ak < 13; ++ak) {
                    int e = dd*13 + ak;
                    float we = ((const float*)w)[e];
                    acc[ak] = fmaf(v[dd], we, acc[ak]);
                }
        }
    }
    // pass B (rare boundary waves): weight row mi+1, exact per-(tk,ak) select
    if (rstar < 13) {
        float accB[13];
#pragma unroll
        for (int j = 0; j < 13; ++j) accB[j] = 0.f;
        const float4* __restrict__ wr = (const float4*)(weff3 + (size_t)(hk*14 + mi + 1)*WROW);
        for (int d4 = 0; d4 < 64; ++d4) {
            float4 w[13];
#pragma unroll
            for (int i = 0; i < 13; ++i) w[i] = wr[d4*13 + i];
            float v[4];
#pragma unroll
            for (int dd = 0; dd < 4; ++dd) v[dd] = Vt[(4*d4+dd)*VT_S + tk];
#pragma unroll
            for (int dd = 0; dd < 4; ++dd)
#pragma unroll
                for (int ak = 0; ak < 13; ++ak) {
                    int e = dd*13 + ak;
                    float we = ((const float*)w)[e];
                    accB[ak] = fmaf(v[dd], we, accB[ak]);
                }
        }
#pragma unroll
        for (int j = 0; j < 13; ++j)
            if (13*tk + j >= 60*rstar) acc[j] = accB[j];
    }

    // ---- phased softmax+AV over 5 u-ranges; all wave-private (no block barriers)
    float* myC = Cb + hk*C_S;
    int dh = lane >> 2, cc = lane & 3;
    const float* vrow = Vt + (hk*16 + dh)*VT_S;
    const int ULO[5] = {0, 180, 360, 540, 720};
    const int UHI[5] = {180, 360, 540, 720, 780};
    const int RLO[5] = {0, 3, 6, 9, 12};
    const int RHI[5] = {3, 6, 9, 12, 13};
#pragma unroll
    for (int p = 0; p < 5; ++p) {
        int ulo = ULO[p], uhi = UHI[p];
        if (tk < NT) {
#pragma unroll
            for (int j = 0; j < 13; ++j) {
                int u = 13*tk + j;
                if (u >= ulo && u < uhi) myC[u - ulo] = acc[j];
            }
        }
        __asm__ __volatile__("s_waitcnt lgkmcnt(0)" ::: "memory");
        for (int r = RLO[p]; r < RHI[p]; ++r) {
            int n = hb13 + r;
            int m = n >> 10;                         // exact weight/bias variant for this row
            int brow = (m*16 + hk)*13;
            float logit = -1e30f;
            if (lane < NT) {
                int u  = r*60 + lane;
                int ak = u % 13;
                logit = (myC[u - ulo] + beff2[brow + ak]) * 0.5f;
            }
            float mx = logit;
#pragma unroll
            for (int off = 32; off; off >>= 1) mx = fmaxf(mx, __shfl_xor(mx, off));
            float e = (lane < NT) ? __expf(logit - mx) : 0.f;
            float s = e;
#pragma unroll
            for (int off = 32; off; off >>= 1) s += __shfl_xor(s, off);
            float attn = e / s;
            // store attn in-place over the consumed logits (same-wave, in-order LDS)
            if (lane < NT) myC[r*60 - ulo + lane] = attn;
            __asm__ __volatile__("s_waitcnt lgkmcnt(0)" ::: "memory");
            // AV: lane = dh*4+cc; t = cc+4j covers 0..59 exactly
            float a = 0.f;
#pragma unroll
            for (int j = 0; j < 15; ++j) {
                int t = cc + 4*j;
                a = fmaf(myC[r*60 - ulo + t], vrow[t], a);
            }
            a += __shfl_xor(a, 1);
            a += __shfl_xor(a, 2);
            if (cc == 0) attout[(size_t)n*NDH + dh] = a;
        }
    }
}

// ---------------- K3: MLP + BN(eval) + ReLU + GroupNorm(16,128); 8 rows/block
__launch_bounds__(1024)
__global__ void ltae_mlp(const float* __restrict__ attout, const float* __restrict__ W1,
                         const float* __restrict__ b1, const float* __restrict__ bnw,
                         const float* __restrict__ bnb, const float* __restrict__ bnrm,
                         const float* __restrict__ bnrv, const float* __restrict__ gow,
                         const float* __restrict__ gob, float* __restrict__ out) {
    __shared__ float f[8][NDM];
    int tid = threadIdx.x;
    int sl  = tid >> 7;          // 0..7 row slot
    int j   = tid & 127;
    int sid = (blockIdx.x << 3) + sl;   // sid = a2*1024 + b2
    int a2  = sid >> 10, b2 = sid & 1023;
    // stage 8 rows of gathered features
    for (int k = tid; k < 8*NDM; k += 1024) {
        int s = k >> 8, c = k & 255;
        int sid2 = (blockIdx.x << 3) + s;
        int aa = sid2 >> 10, bb = sid2 & 1023;
        int h2 = c >> 4, dhh = c & 15;
        f[s][c] = attout[((size_t)((aa*16 + h2)*1024 + bb))*NDH + dhh];
    }
    __syncthreads();
    const float* fr = f[sl];
    const float* w  = &W1[(size_t)j*NDM];
    float acc = b1[j];
    for (int c = 0; c < NDM; c += 4) {
        float4 wv = *(const float4*)&w[c];
        acc += wv.x*fr[c] + wv.y*fr[c+1] + wv.z*fr[c+2] + wv.w*fr[c+3];
    }
    float y = (acc - bnrm[j]) * rsqrtf(bnrv[j] + 1e-5f) * bnw[j] + bnb[j];
    y = fmaxf(y, 0.f);
    float s1 = y, s2 = y*y;
#pragma unroll
    for (int off = 1; off < 8; off <<= 1) {
        s1 += __shfl_xor(s1, off);
        s2 += __shfl_xor(s2, off);
    }
    float mean = s1 * 0.125f;
    float var  = s2 * 0.125f - mean*mean;
    float o = (y - mean) * rsqrtf(var + 1e-5f) * gow[j] + gob[j];
    out[((size_t)b2*NA + a2)*NMO + j] = o;
}

extern "C" void kernel_launch(void* const* d_in, const int* in_sizes, int n_in,
                              void* d_out, int out_size, void* d_ws, size_t ws_size,
                              hipStream_t stream) {
    const float* x    = (const float*)d_in[0];
    const float* Wc   = (const float*)d_in[1];
    const float* bc   = (const float*)d_in[2];
    const float* gnw  = (const float*)d_in[3];
    const float* gnb  = (const float*)d_in[4];
    const float* Q    = (const float*)d_in[5];
    const float* Wk   = (const float*)d_in[6];
    const float* bk   = (const float*)d_in[7];
    const float* W1   = (const float*)d_in[8];
    const float* b1   = (const float*)d_in[9];
    const float* bnw  = (const float*)d_in[10];
    const float* bnb  = (const float*)d_in[11];
    const float* bnrm = (const float*)d_in[12];
    const float* bnrv = (const float*)d_in[13];
    const float* gow  = (const float*)d_in[14];
    const float* gob  = (const float*)d_in[15];

    float* ws     = (float*)d_ws;
    float* weff3  = ws + OFF_WEFF;
    float* beff2  = ws + OFF_BEFF;
    float* attout = ws + OFF_ATT;
    float* outp   = (float*)d_out;

    hipLaunchKernelGGL(ltae_weff, dim3(NH*14), dim3(256), 0, stream, Q, Wk, bk, weff3, beff2);
    hipFuncSetAttribute((const void*)ltae_fused,
                        hipFuncAttributeMaxDynamicSharedMemorySize, K2_LDS_BYTES);
    hipLaunchKernelGGL(ltae_fused, dim3(NB), dim3(1024), K2_LDS_BYTES, stream,
                       x, Wc, bc, gnw, gnb, weff3, beff2, attout);
    hipLaunchKernelGGL(ltae_mlp, dim3(NA*NB/8), dim3(1024), 0, stream,
                       attout, W1, b1, bnw, bnb, bnrm, bnrv, gow, gob, outp);
}